// Round 6
// baseline (118.053 us; speedup 1.0000x reference)
//
#include <hip/hip_runtime.h>

// SwitchLinear: out[b] = x[b] @ (W[route[b]] + Wf)^T + bias[route[b]] + bf
// B=4096, IN=OUT=256, E=16.
//
// SINGLE dispatch, zero workspace. Grid (32 j, 4 g, 16 e), 256 threads.
// Block (j,g,e): sorted-token window [16j,16j+16) of expert e, outs [64g,+64);
// wave w owns outs [64g+16w, +16) (one MFMA accumulator per wave -> ~4300
// useful waves, ~5 waves/SIMD: latency-hiding that R4's fused version lacked).
//
//  phase 1: ballot-scan ridx in 16 rounds of 256 tokens (deterministic rank ->
//           all blocks of expert e agree); uniform early break once the
//           window is covered. No histogram pass, no stok buffer.
//  phase 2: 16x16 (K=256) MFMA tile. fp32 W/Wf/x loaded with explicit depth-2
//           register double-buffering (forces memory-level parallelism; R4's
//           failure was the compiler serializing these loads at 36 VGPRs),
//           folded W+Wf and packed to bf16 in-register. Same numerics as a
//           prep pass: fp32 add, then bf16 round-nearest-even.
//  epilogue: + bias[e] + bias_fact, fp32 out. Each output row written by
//           exactly one block (token -> one expert; n-ranges disjoint).

#define B_TOK 4096
#define IN_F 256
#define OUT_F 256
#define NEXP 16
#define WEL (OUT_F * IN_F)  // 65536 elems per expert weight

typedef __attribute__((ext_vector_type(8))) short bhalf8;  // 8 bf16 = 4 VGPRs
typedef __attribute__((ext_vector_type(4))) float v4f;     // MFMA accumulator

__device__ __forceinline__ unsigned short f2bf(float f) {
    unsigned u = __float_as_uint(f);
    u += 0x7FFFu + ((u >> 16) & 1u);  // round-nearest-even
    return (unsigned short)(u >> 16);
}

__device__ __forceinline__ bhalf8 pack_bf8(const float4& a, const float4& b) {
    bhalf8 v;
    v[0] = (short)f2bf(a.x); v[1] = (short)f2bf(a.y);
    v[2] = (short)f2bf(a.z); v[3] = (short)f2bf(a.w);
    v[4] = (short)f2bf(b.x); v[5] = (short)f2bf(b.y);
    v[6] = (short)f2bf(b.z); v[7] = (short)f2bf(b.w);
    return v;
}

__device__ __forceinline__ bhalf8 fold_bf8(const float4& w0, const float4& w1,
                                           const float4& f0, const float4& f1) {
    bhalf8 v;
    v[0] = (short)f2bf(w0.x + f0.x); v[1] = (short)f2bf(w0.y + f0.y);
    v[2] = (short)f2bf(w0.z + f0.z); v[3] = (short)f2bf(w0.w + f0.w);
    v[4] = (short)f2bf(w1.x + f1.x); v[5] = (short)f2bf(w1.y + f1.y);
    v[6] = (short)f2bf(w1.z + f1.z); v[7] = (short)f2bf(w1.w + f1.w);
    return v;
}

__global__ __launch_bounds__(256) void k_fused(
    const float* __restrict__ x, const int* __restrict__ ridx,
    const float* __restrict__ w, const float* __restrict__ wf,
    const float* __restrict__ bias, const float* __restrict__ bf,
    float* __restrict__ out) {
    __shared__ int wc[4];
    __shared__ int stk[16];

    int e = blockIdx.z;
    int j = blockIdx.x;
    int g = blockIdx.y;
    int tid = threadIdx.x;
    int wave = tid >> 6;
    int lane = tid & 63;
    int start = j * 16;
    int end = start + 16;

    // ---- phase 1: rank-scan ridx, collect window tokens, early break ----
    int running = 0;
    for (int c = 0; c < 16; ++c) {
        int tok = c * 256 + tid;
        bool m = (ridx[tok] == e);
        unsigned long long mask = __ballot(m);
        if (lane == 0) wc[wave] = (int)__popcll(mask);
        __syncthreads();
        int wbase = running;
        for (int wv = 0; wv < wave; ++wv) wbase += wc[wv];
        if (m) {
            int rank = wbase + (int)__popcll(mask & ((1ull << lane) - 1ull));
            int slot = rank - start;
            if (slot >= 0 && slot < 16) stk[slot] = tok;
        }
        running += wc[0] + wc[1] + wc[2] + wc[3];
        __syncthreads();          // wc reused next round
        if (running >= end) break;  // block-uniform
    }
    // running >= actual coverage of this window: if we broke early the window
    // is full (rows=16); else running == cnt.
    int rows = running - start;
    if (rows <= 0) return;  // block-uniform
    if (rows > 16) rows = 16;
    if (tid < 16 && tid >= rows) stk[tid] = stk[0];  // pad with a valid token
    __syncthreads();

    // ---- phase 2: MFMA with in-register W+Wf fold, depth-2 reg pipeline ----
    int l15 = lane & 15;
    int quad = lane >> 4;
    int n0 = g * 64 + wave * 16;

    const float* xr = x + stk[l15] * IN_F + quad * 8;
    const float* wr = w + e * WEL + (n0 + l15) * IN_F + quad * 8;
    const float* fr = wf + (n0 + l15) * IN_F + quad * 8;

    float4 xa[2], xb[2], wa[2], wb[2], fa[2], fb[2];
    xa[0] = *(const float4*)(xr);     xb[0] = *(const float4*)(xr + 4);
    wa[0] = *(const float4*)(wr);     wb[0] = *(const float4*)(wr + 4);
    fa[0] = *(const float4*)(fr);     fb[0] = *(const float4*)(fr + 4);

    v4f acc = (v4f){0.f, 0.f, 0.f, 0.f};
    #pragma unroll
    for (int ks = 0; ks < 8; ++ks) {
        int cur = ks & 1, nxt = cur ^ 1;
        if (ks < 7) {  // issue next-step loads before consuming current
            int o = (ks + 1) * 32;
            xa[nxt] = *(const float4*)(xr + o); xb[nxt] = *(const float4*)(xr + o + 4);
            wa[nxt] = *(const float4*)(wr + o); wb[nxt] = *(const float4*)(wr + o + 4);
            fa[nxt] = *(const float4*)(fr + o); fb[nxt] = *(const float4*)(fr + o + 4);
        }
        bhalf8 a = pack_bf8(xa[cur], xb[cur]);
        bhalf8 b = fold_bf8(wa[cur], wb[cur], fa[cur], fb[cur]);
        acc = __builtin_amdgcn_mfma_f32_16x16x32_bf16(a, b, acc, 0, 0, 0);
    }

    // ---- epilogue ----
    int m = n0 + l15;
    float bb = bias[e * OUT_F + m] + bf[m];
    #pragma unroll
    for (int r = 0; r < 4; ++r) {
        int row = quad * 4 + r;
        if (row < rows) out[stk[row] * OUT_F + m] = acc[r] + bb;
    }
}

extern "C" void kernel_launch(void* const* d_in, const int* in_sizes, int n_in,
                              void* d_out, int out_size, void* d_ws, size_t ws_size,
                              hipStream_t stream) {
    const float* x = (const float*)d_in[0];
    const int* ridx = (const int*)d_in[1];
    const float* w = (const float*)d_in[2];
    const float* wf = (const float*)d_in[3];
    const float* bias = (const float*)d_in[4];
    const float* bf = (const float*)d_in[5];
    float* out = (float*)d_out;

    // m-capacity 32 windows/expert = 512 tokens; counts ~ Binomial(4096,1/16)
    // (mean 256, sigma 15.5) -> 16.5 sigma headroom.
    k_fused<<<dim3(32, 4, NEXP), 256, 0, stream>>>(x, ridx, w, wf, bias, bf, out);
}

// Round 7
// 88.269 us; speedup vs baseline: 1.3374x; 1.3374x over previous
//
#include <hip/hip_runtime.h>

// SwitchLinear: out[b] = x[b] @ (W[route[b]] + Wf)^T + bias[route[b]] + bf
// B=4096, IN=OUT=256, E=16.
//
// 2-dispatch pipeline, XCD-pinned:
//  Workgroup->XCD assignment on MI355X is round-robin over linear block id
//  (id % 8). Both kernels use 1-D grids with block id ≡ expert (mod 16), so
//  ALL blocks touching expert e land on XCD e%8: wsum[e] is written and read
//  within one XCD's L2 (no cross-XCD HBM re-fetch — R6 showed 20 MB fetched
//  for 8.5 MB unique), and each token's xbf row is fetched once.
//
//  1. k_prep (1040 blocks):
//     lid 0..511   : wsum = bf16(W+Wf); lid&15 = expert  -> XCD-pinned
//     lid 512..1023: xbf  = bf16(x)
//     lid 1024..1039: per-source-block expert histograms part[16][16]
//  2. k_gemm (2048 blocks): lid&15 = expert -> same XCD as its wsum.
//     Block covers sorted-token window [16j,+16) x outs [64g,+64); each wave
//     owns a 16x16 MFMA tile, all 8 A-frags + 8 B-frags prefetched to regs
//     (bf16 operands -> no in-loop fold for the compiler to serialize).
//     Token ids reconstructed from part[] + 1-2 ballot rounds.

#define B_TOK 4096
#define IN_F 256
#define OUT_F 256
#define NEXP 16
#define WEL (OUT_F * IN_F)  // 65536 elems per expert weight
#define NSB 16              // source blocks of 256 tokens each

typedef __attribute__((ext_vector_type(8))) short bhalf8;  // 8 bf16 = 4 VGPRs
typedef __attribute__((ext_vector_type(4))) float v4f;     // MFMA accumulator

// ws layout (bytes)
#define WSUM_OFF 0u         // ushort[1048576]  bf16(W[e]+Wf)
#define XBF_OFF 2097152u    // ushort[1048576]  bf16(x)
#define PART_OFF 4194304u   // int[16*16]       part[sb][e] histogram

__device__ __forceinline__ unsigned short f2bf(float f) {
    unsigned u = __float_as_uint(f);
    u += 0x7FFFu + ((u >> 16) & 1u);  // round-nearest-even
    return (unsigned short)(u >> 16);
}

__global__ __launch_bounds__(256) void k_prep(
    const float* __restrict__ x, const int* __restrict__ ridx,
    const float* __restrict__ w, const float* __restrict__ wf,
    unsigned short* __restrict__ wsum, unsigned short* __restrict__ xbf,
    int* __restrict__ part) {
    int lid = blockIdx.x;
    int tid = threadIdx.x;
    if (lid < 512) {
        // expert-pinned W+Wf fold: e = lid&15 -> XCD e%8
        int e = lid & 15;
        int t = lid >> 4;  // chunk 0..31 within expert
        int id = e * WEL + t * 2048 + tid * 8;
        int fo = t * 2048 + tid * 8;
        const float4 a0 = *(const float4*)(w + id);
        const float4 a1 = *(const float4*)(w + id + 4);
        const float4 f0 = *(const float4*)(wf + fo);
        const float4 f1 = *(const float4*)(wf + fo + 4);
        bhalf8 v;
        v[0] = (short)f2bf(a0.x + f0.x); v[1] = (short)f2bf(a0.y + f0.y);
        v[2] = (short)f2bf(a0.z + f0.z); v[3] = (short)f2bf(a0.w + f0.w);
        v[4] = (short)f2bf(a1.x + f1.x); v[5] = (short)f2bf(a1.y + f1.y);
        v[6] = (short)f2bf(a1.z + f1.z); v[7] = (short)f2bf(a1.w + f1.w);
        *(bhalf8*)(wsum + id) = v;
    } else if (lid < 1024) {
        int id = ((lid - 512) * 256 + tid) * 8;
        const float4 a0 = *(const float4*)(x + id);
        const float4 a1 = *(const float4*)(x + id + 4);
        bhalf8 v;
        v[0] = (short)f2bf(a0.x); v[1] = (short)f2bf(a0.y);
        v[2] = (short)f2bf(a0.z); v[3] = (short)f2bf(a0.w);
        v[4] = (short)f2bf(a1.x); v[5] = (short)f2bf(a1.y);
        v[6] = (short)f2bf(a1.z); v[7] = (short)f2bf(a1.w);
        *(bhalf8*)(xbf + id) = v;
    } else {
        __shared__ int h[NEXP];
        if (tid < NEXP) h[tid] = 0;
        __syncthreads();
        int sb = lid - 1024;
        atomicAdd(&h[ridx[sb * 256 + tid]], 1);
        __syncthreads();
        if (tid < NEXP) part[sb * NEXP + tid] = h[tid];
    }
}

// 2048 blocks 1-D: e = lid&15 (XCD-pinned), t = lid>>4, j = t&31, g = t>>5.
// A-frag: lane holds xbf[tok(lane&15)][(lane>>4)*8 + ks*32 + 0..7]
// B-frag: lane holds wsum[e][n0+(lane&15)][(lane>>4)*8 + ks*32 + 0..7]
// D (verified convention from R1-R5, passed): epilogue writes
// out[stk[quad*4+reg]][n0+l15].
__global__ __launch_bounds__(256) void k_gemm(
    const unsigned short* __restrict__ wsum, const unsigned short* __restrict__ xbf,
    const int* __restrict__ part, const int* __restrict__ ridx,
    const float* __restrict__ bias, const float* __restrict__ bf,
    float* __restrict__ out) {
    __shared__ int pc[NSB];
    __shared__ int pfx[NSB + 1];
    __shared__ int wc[4];
    __shared__ int stk[16];

    int lid = blockIdx.x;
    int e = lid & 15;
    int t = lid >> 4;
    int j = t & 31;
    int g = t >> 5;
    int tid = threadIdx.x;

    if (tid < NSB) pc[tid] = part[tid * NEXP + e];
    __syncthreads();
    if (tid == 0) {
        int a = 0;
        for (int sb = 0; sb < NSB; ++sb) { pfx[sb] = a; a += pc[sb]; }
        pfx[NSB] = a;
    }
    __syncthreads();
    int cnt = pfx[NSB];
    int start = j * 16;
    if (start >= cnt) return;  // block-uniform
    int rem = cnt - start;
    int rows = rem < 16 ? rem : 16;
    int end = start + rows;

    int wave = tid >> 6;
    int lane = tid & 63;

    for (int sb = 0; sb < NSB; ++sb) {
        if (pfx[sb + 1] <= start || pfx[sb] >= end) continue;  // block-uniform
        int tok = sb * 256 + tid;
        bool m = (ridx[tok] == e);
        unsigned long long mask = __ballot(m);
        if (lane == 0) wc[wave] = (int)__popcll(mask);
        __syncthreads();
        int wbase = 0;
        for (int wv = 0; wv < wave; ++wv) wbase += wc[wv];
        int rank = wbase + (int)__popcll(mask & ((1ull << lane) - 1ull));
        int slot = pfx[sb] + rank;
        if (m && slot >= start && slot < end) stk[slot - start] = tok;
        __syncthreads();
    }
    if (tid < 16 && tid >= rows) stk[tid] = stk[0];  // pad with a valid token
    __syncthreads();

    int l15 = lane & 15;
    int quad = lane >> 4;
    int n0 = g * 64 + wave * 16;

    const unsigned short* xr = xbf + stk[l15] * IN_F + quad * 8;
    const unsigned short* wr = wsum + e * WEL + (n0 + l15) * IN_F + quad * 8;

    // Prefetch ALL fragments (bf16 -> 2 dwordx4 per ks), then MFMA chain.
    bhalf8 areg[8], breg[8];
    #pragma unroll
    for (int ks = 0; ks < 8; ++ks) {
        areg[ks] = *(const bhalf8*)(xr + ks * 32);
        breg[ks] = *(const bhalf8*)(wr + ks * 32);
    }
    v4f acc = (v4f){0.f, 0.f, 0.f, 0.f};
    #pragma unroll
    for (int ks = 0; ks < 8; ++ks)
        acc = __builtin_amdgcn_mfma_f32_16x16x32_bf16(areg[ks], breg[ks], acc, 0, 0, 0);

    int m = n0 + l15;
    float bb = bias[e * OUT_F + m] + bf[m];
    #pragma unroll
    for (int r = 0; r < 4; ++r) {
        int row = quad * 4 + r;
        if (row < rows) out[stk[row] * OUT_F + m] = acc[r] + bb;
    }
}

extern "C" void kernel_launch(void* const* d_in, const int* in_sizes, int n_in,
                              void* d_out, int out_size, void* d_ws, size_t ws_size,
                              hipStream_t stream) {
    const float* x = (const float*)d_in[0];
    const int* ridx = (const int*)d_in[1];
    const float* w = (const float*)d_in[2];
    const float* wf = (const float*)d_in[3];
    const float* bias = (const float*)d_in[4];
    const float* bf = (const float*)d_in[5];
    float* out = (float*)d_out;
    char* ws = (char*)d_ws;

    unsigned short* wsum = (unsigned short*)(ws + WSUM_OFF);
    unsigned short* xbf = (unsigned short*)(ws + XBF_OFF);
    int* part = (int*)(ws + PART_OFF);

    k_prep<<<1040, 256, 0, stream>>>(x, ridx, w, wf, wsum, xbf, part);
    // m-capacity 32 windows/expert = 512 tokens; counts ~ Binomial(4096,1/16)
    // (mean 256, sigma 15.5) -> 16.5 sigma headroom.
    k_gemm<<<2048, 256, 0, stream>>>(wsum, xbf, part, ridx, bias, bf, out);
}

// Round 8
// 85.708 us; speedup vs baseline: 1.3774x; 1.0299x over previous
//
#include <hip/hip_runtime.h>

// SwitchLinear: out[b] = x[b] @ (W[route[b]] + Wf)^T + bias[route[b]] + bf
// B=4096, IN=OUT=256, E=16.
//
// Consolidated best-of-measured (R3 shape + R7 pinning, dead weight removed):
//  1. k_prep (528 blocks): wsum = bf16(W[e]+Wf) XCD-pinned by expert (lid&15),
//     + per-source-block expert histograms part[16][16]. No x conversion
//     (each x row is consumed by exactly one gemm block -> direct fp32 read
//     is strictly less traffic), no bias pass (folded in gemm epilogue).
//  2. k_gemm (512 blocks, lid&15 = expert -> same XCD as wsum[e]):
//     block = sorted-token window [16j,+16) x ALL 256 outs, K=256.
//     Wave w owns outs [64w,+64) as 4 MFMA accumulators (ILP x4).
//     A = fp32 x converted in-register; B = bf16 wsum, all 4 n-subtile
//     fragments loaded per ks-step before the 4-MFMA group (MLP).
//     Token ids reconstructed from part[] + 1-2 ballot rounds.

#define B_TOK 4096
#define IN_F 256
#define OUT_F 256
#define NEXP 16
#define WEL (OUT_F * IN_F)  // 65536 elems per expert weight
#define NSB 16              // source blocks of 256 tokens each

typedef __attribute__((ext_vector_type(8))) short bhalf8;  // 8 bf16 = 4 VGPRs
typedef __attribute__((ext_vector_type(4))) float v4f;     // MFMA accumulator

// ws layout (bytes)
#define WSUM_OFF 0u         // ushort[1048576]  bf16(W[e]+Wf)
#define PART_OFF 2097152u   // int[16*16]       part[sb][e] histogram

__device__ __forceinline__ unsigned short f2bf(float f) {
    unsigned u = __float_as_uint(f);
    u += 0x7FFFu + ((u >> 16) & 1u);  // round-nearest-even
    return (unsigned short)(u >> 16);
}

// lid 0..511 : wsum = bf16(W+Wf), e = lid&15 (XCD-pinned), 8 elems/thread
// lid 512..527: histogram part[sb][e]
__global__ __launch_bounds__(256) void k_prep(
    const int* __restrict__ ridx, const float* __restrict__ w,
    const float* __restrict__ wf, unsigned short* __restrict__ wsum,
    int* __restrict__ part) {
    int lid = blockIdx.x;
    int tid = threadIdx.x;
    if (lid < 512) {
        int e = lid & 15;
        int t = lid >> 4;  // chunk 0..31 within expert
        int fo = t * 2048 + tid * 8;
        int id = e * WEL + fo;
        const float4 a0 = *(const float4*)(w + id);
        const float4 a1 = *(const float4*)(w + id + 4);
        const float4 f0 = *(const float4*)(wf + fo);
        const float4 f1 = *(const float4*)(wf + fo + 4);
        bhalf8 v;
        v[0] = (short)f2bf(a0.x + f0.x); v[1] = (short)f2bf(a0.y + f0.y);
        v[2] = (short)f2bf(a0.z + f0.z); v[3] = (short)f2bf(a0.w + f0.w);
        v[4] = (short)f2bf(a1.x + f1.x); v[5] = (short)f2bf(a1.y + f1.y);
        v[6] = (short)f2bf(a1.z + f1.z); v[7] = (short)f2bf(a1.w + f1.w);
        *(bhalf8*)(wsum + id) = v;
    } else {
        __shared__ int h[NEXP];
        if (tid < NEXP) h[tid] = 0;
        __syncthreads();
        int sb = lid - 512;
        atomicAdd(&h[ridx[sb * 256 + tid]], 1);
        __syncthreads();
        if (tid < NEXP) part[sb * NEXP + tid] = h[tid];
    }
}

// 512 blocks: e = lid&15 (XCD pin), j = lid>>4. Window [16j,+16) x 256 outs.
// A-frag: lane holds bf16(x[tok(lane&15)][(lane>>4)*8 + ks*32 + 0..7])
// B-frag: lane holds wsum[e][n0+(lane&15)][(lane>>4)*8 + ks*32 + 0..7]
// Epilogue (convention verified R1-R7): out[stk[quad*4+r]][m], m = n-index
// from l15.
__global__ __launch_bounds__(256) void k_gemm(
    const unsigned short* __restrict__ wsum, const float* __restrict__ x,
    const int* __restrict__ part, const int* __restrict__ ridx,
    const float* __restrict__ bias, const float* __restrict__ bf,
    float* __restrict__ out) {
    __shared__ int pc[NSB];
    __shared__ int pfx[NSB + 1];
    __shared__ int wc[4];
    __shared__ int stk[16];

    int lid = blockIdx.x;
    int e = lid & 15;
    int j = lid >> 4;
    int tid = threadIdx.x;

    if (tid < NSB) pc[tid] = part[tid * NEXP + e];
    __syncthreads();
    if (tid == 0) {
        int a = 0;
        for (int sb = 0; sb < NSB; ++sb) { pfx[sb] = a; a += pc[sb]; }
        pfx[NSB] = a;
    }
    __syncthreads();
    int cnt = pfx[NSB];
    int start = j * 16;
    if (start >= cnt) return;  // block-uniform
    int rem = cnt - start;
    int rows = rem < 16 ? rem : 16;
    int end = start + rows;

    int wave = tid >> 6;
    int lane = tid & 63;

    for (int sb = 0; sb < NSB; ++sb) {
        if (pfx[sb + 1] <= start || pfx[sb] >= end) continue;  // block-uniform
        int tok = sb * 256 + tid;
        bool m = (ridx[tok] == e);
        unsigned long long mask = __ballot(m);
        if (lane == 0) wc[wave] = (int)__popcll(mask);
        __syncthreads();
        int wbase = 0;
        for (int wv = 0; wv < wave; ++wv) wbase += wc[wv];
        int rank = wbase + (int)__popcll(mask & ((1ull << lane) - 1ull));
        int slot = pfx[sb] + rank;
        if (m && slot >= start && slot < end) stk[slot - start] = tok;
        __syncthreads();
    }
    if (tid < 16 && tid >= rows) stk[tid] = stk[0];  // pad with a valid token
    __syncthreads();

    int l15 = lane & 15;
    int quad = lane >> 4;

    const float* xr = x + stk[l15] * IN_F + quad * 8;
    const unsigned short* wr = wsum + e * WEL + (wave * 64 + l15) * IN_F + quad * 8;

    v4f acc[4];
    #pragma unroll
    for (int n = 0; n < 4; ++n) acc[n] = (v4f){0.f, 0.f, 0.f, 0.f};

    #pragma unroll
    for (int ks = 0; ks < 8; ++ks) {
        const float4 a0 = *(const float4*)(xr + ks * 32);
        const float4 a1 = *(const float4*)(xr + ks * 32 + 4);
        // issue all 4 B loads before any MFMA (MLP within the step)
        bhalf8 b0 = *(const bhalf8*)(wr + 0 * 16 * IN_F + ks * 32);
        bhalf8 b1 = *(const bhalf8*)(wr + 1 * 16 * IN_F + ks * 32);
        bhalf8 b2 = *(const bhalf8*)(wr + 2 * 16 * IN_F + ks * 32);
        bhalf8 b3 = *(const bhalf8*)(wr + 3 * 16 * IN_F + ks * 32);
        bhalf8 a;
        a[0] = (short)f2bf(a0.x); a[1] = (short)f2bf(a0.y);
        a[2] = (short)f2bf(a0.z); a[3] = (short)f2bf(a0.w);
        a[4] = (short)f2bf(a1.x); a[5] = (short)f2bf(a1.y);
        a[6] = (short)f2bf(a1.z); a[7] = (short)f2bf(a1.w);
        acc[0] = __builtin_amdgcn_mfma_f32_16x16x32_bf16(a, b0, acc[0], 0, 0, 0);
        acc[1] = __builtin_amdgcn_mfma_f32_16x16x32_bf16(a, b1, acc[1], 0, 0, 0);
        acc[2] = __builtin_amdgcn_mfma_f32_16x16x32_bf16(a, b2, acc[2], 0, 0, 0);
        acc[3] = __builtin_amdgcn_mfma_f32_16x16x32_bf16(a, b3, acc[3], 0, 0, 0);
    }

    #pragma unroll
    for (int n = 0; n < 4; ++n) {
        int m = wave * 64 + n * 16 + l15;
        float bb = bias[e * OUT_F + m] + bf[m];
        #pragma unroll
        for (int r = 0; r < 4; ++r) {
            int row = quad * 4 + r;
            if (row < rows) out[stk[row] * OUT_F + m] = acc[n][r] + bb;
        }
    }
}

extern "C" void kernel_launch(void* const* d_in, const int* in_sizes, int n_in,
                              void* d_out, int out_size, void* d_ws, size_t ws_size,
                              hipStream_t stream) {
    const float* x = (const float*)d_in[0];
    const int* ridx = (const int*)d_in[1];
    const float* w = (const float*)d_in[2];
    const float* wf = (const float*)d_in[3];
    const float* bias = (const float*)d_in[4];
    const float* bf = (const float*)d_in[5];
    float* out = (float*)d_out;
    char* ws = (char*)d_ws;

    unsigned short* wsum = (unsigned short*)(ws + WSUM_OFF);
    int* part = (int*)(ws + PART_OFF);

    k_prep<<<528, 256, 0, stream>>>(ridx, w, wf, wsum, part);
    // m-capacity 32 windows/expert = 512 tokens; counts ~ Binomial(4096,1/16)
    // (mean 256, sigma 15.5) -> 16.5 sigma headroom.
    k_gemm<<<512, 256, 0, stream>>>(wsum, x, part, ridx, bias, bf, out);
}